// Round 2
// baseline (823.030 us; speedup 1.0000x reference)
//
#include <hip/hip_runtime.h>

typedef __bf16 bf16;
typedef __bf16 bf16x8 __attribute__((ext_vector_type(8)));
typedef float  f32x4  __attribute__((ext_vector_type(4)));

#define MFMA16(a,b,c) __builtin_amdgcn_mfma_f32_16x16x32_bf16((a),(b),(c),0,0,0)

constexpr int Bn = 8, Sn = 4096, En = 2048, Ln = 64, Hn = 128;
constexpr int Mrows = Bn * Sn; // 32768

// ---------------- transpose + fp32->bf16: in[K][N] -> out[N][K] ----------------
__global__ __launch_bounds__(256) void transpose_cvt(const float* __restrict__ in,
                                                     bf16* __restrict__ out,
                                                     int K, int N) {
    int tid = blockIdx.x * 256 + threadIdx.x;
    if (tid >= K * N) return;
    int k = tid / N, n = tid - k * N;
    out[n * K + k] = (bf16)in[tid];
}

// ---------------- fused latent+q GEMM: C = x @ [w_dkv | w_q] ----------------
// per block: 64 rows (4 waves x 16), all 192 cols (12 n-tiles: 0-3 latent, 4-11 q)
__global__ __launch_bounds__(256) void gemm_xw(const float* __restrict__ x,
                                               const bf16* __restrict__ wtd,   // [64][2048]
                                               const bf16* __restrict__ wtq,   // [128][2048]
                                               float* __restrict__ latent_out, // [32768][64] fp32
                                               bf16* __restrict__ q_out) {     // [32768][128] bf16
    const int lane = threadIdx.x & 63;
    const int wave = threadIdx.x >> 6;
    const int col  = lane & 15, quad = lane >> 4;
    const int m0   = blockIdx.x * 64 + wave * 16;
    f32x4 acc[12];
#pragma unroll
    for (int t = 0; t < 12; ++t) acc[t] = (f32x4){0.f, 0.f, 0.f, 0.f};
    const float* arow = x + (size_t)(m0 + col) * En;
    for (int ks = 0; ks < En / 32; ++ks) {
        const int k0 = ks * 32 + quad * 8;
        f32x4 a0 = *(const f32x4*)(arow + k0);
        f32x4 a1 = *(const f32x4*)(arow + k0 + 4);
        bf16x8 a;
#pragma unroll
        for (int j = 0; j < 4; ++j) { a[j] = (bf16)a0[j]; a[4 + j] = (bf16)a1[j]; }
#pragma unroll
        for (int t = 0; t < 12; ++t) {
            const bf16* bp = (t < 4) ? (wtd + (size_t)(t * 16 + col) * En + k0)
                                     : (wtq + (size_t)((t - 4) * 16 + col) * En + k0);
            bf16x8 b = *(const bf16x8*)bp;
            acc[t] = MFMA16(a, b, acc[t]);
        }
    }
#pragma unroll
    for (int t = 0; t < 12; ++t)
#pragma unroll
        for (int r = 0; r < 4; ++r) {
            int row = m0 + quad * 4 + r;
            if (t < 4) latent_out[(size_t)row * Ln + t * 16 + col] = acc[t][r];
            else       q_out[(size_t)row * Hn + (t - 4) * 16 + col] = (bf16)acc[t][r];
        }
}

// ---------------- k/v decompression: out[m][h] = sum_l latent[m][l]*w[l][h] ----------------
__global__ __launch_bounds__(256) void decompress_k(const float* __restrict__ latent, // [32768][64] fp32
                                                    const float* __restrict__ w,      // [64][128] fp32
                                                    bf16* __restrict__ out) {         // [32768][128] bf16
    int tid = blockIdx.x * 256 + threadIdx.x;
    int m = tid >> 7, h = tid & 127;
    const float* lrow = latent + (size_t)m * Ln;
    float acc = 0.f;
#pragma unroll
    for (int l = 0; l < Ln; ++l)
        acc += lrow[l] * w[l * Hn + h];
    out[tid] = (bf16)acc;
}

// ---------------- flash attention, causal, BQ=64 BK=64 D=128 ----------------
__global__ __launch_bounds__(256) void mla_attn(const bf16* __restrict__ qg,
                                                const bf16* __restrict__ kg,
                                                const bf16* __restrict__ vg,
                                                float* __restrict__ outg) {
    __shared__ __align__(16) bf16 Kt[64][136];    // [key][d], +8 pad
    __shared__ __align__(16) bf16 Vt[128][72];    // [d][key], +8 pad
    __shared__ __align__(16) bf16 Pb[4][16][72];  // per-wave P, [row][key], +8 pad
    const int lane = threadIdx.x & 63;
    const int wave = threadIdx.x >> 6;
    const int col  = lane & 15, quad = lane >> 4;
    const int bb    = blockIdx.y;
    const int qtile = (int)gridDim.x - 1 - (int)blockIdx.x; // big blocks first
    const int qbase = qtile * 64;
    const bf16* kb = kg + (size_t)bb * Sn * Hn;
    const bf16* vb = vg + (size_t)bb * Sn * Hn;

    // Q fragments (A-layout): row = lane%16 within wave's 16 rows
    bf16x8 qf[4];
    {
        const bf16* qrow = qg + ((size_t)bb * Sn + qbase + wave * 16 + col) * Hn;
#pragma unroll
        for (int ks = 0; ks < 4; ++ks)
            qf[ks] = *(const bf16x8*)(qrow + ks * 32 + quad * 8);
    }
    f32x4 o[8];
#pragma unroll
    for (int t = 0; t < 8; ++t) o[t] = (f32x4){0.f, 0.f, 0.f, 0.f};
    float m_run[4] = {-3.0e38f, -3.0e38f, -3.0e38f, -3.0e38f};
    float l_run[4] = {0.f, 0.f, 0.f, 0.f};
    const float scale = 0.08838834764831845f; // 1/sqrt(128)

    for (int kt = 0; kt <= qtile; ++kt) {
        __syncthreads();
        // stage K tile [64][128] (direct copy, coalesced)
#pragma unroll
        for (int i = 0; i < 4; ++i) {
            int c = threadIdx.x + i * 256;
            int key = c >> 4, dc = c & 15;
            *(bf16x8*)(&Kt[key][dc * 8]) =
                *(const bf16x8*)(kb + (size_t)(kt * 64 + key) * Hn + dc * 8);
        }
        // stage V tile transposed -> Vt[d][key]
#pragma unroll
        for (int i = 0; i < 4; ++i) {
            int c = threadIdx.x + i * 256;
            int key = c & 63, dc = c >> 6;
            bf16x8 vv = *(const bf16x8*)(vb + (size_t)(kt * 64 + key) * Hn + dc * 8);
#pragma unroll
            for (int j = 0; j < 8; ++j) Vt[dc * 8 + j][key] = vv[j];
        }
        __syncthreads();

        // S = Q K^T for this wave's 16 rows x 64 keys
        f32x4 sa[4];
#pragma unroll
        for (int nt = 0; nt < 4; ++nt) {
            sa[nt] = (f32x4){0.f, 0.f, 0.f, 0.f};
#pragma unroll
            for (int ks = 0; ks < 4; ++ks) {
                bf16x8 bfr = *(const bf16x8*)(&Kt[nt * 16 + col][ks * 32 + quad * 8]);
                sa[nt] = MFMA16(qf[ks], bfr, sa[nt]);
            }
        }
        // scale + causal mask (only diagonal tile needs masking)
        float sc_[4][4];
        if (kt == qtile) {
#pragma unroll
            for (int nt = 0; nt < 4; ++nt)
#pragma unroll
                for (int r = 0; r < 4; ++r) {
                    float s = sa[nt][r] * scale;
                    if (nt * 16 + col > wave * 16 + quad * 4 + r) s = -1.0e30f;
                    sc_[nt][r] = s;
                }
        } else {
#pragma unroll
            for (int nt = 0; nt < 4; ++nt)
#pragma unroll
                for (int r = 0; r < 4; ++r) sc_[nt][r] = sa[nt][r] * scale;
        }
        // online softmax: rows live in quads, reduce across the quad's 16 lanes
        float mt[4];
#pragma unroll
        for (int r = 0; r < 4; ++r)
            mt[r] = fmaxf(fmaxf(sc_[0][r], sc_[1][r]), fmaxf(sc_[2][r], sc_[3][r]));
#pragma unroll
        for (int off = 1; off <= 8; off <<= 1)
#pragma unroll
            for (int r = 0; r < 4; ++r)
                mt[r] = fmaxf(mt[r], __shfl_xor(mt[r], off, 64));
        float alpha[4];
#pragma unroll
        for (int r = 0; r < 4; ++r) {
            float mn = fmaxf(m_run[r], mt[r]);
            alpha[r] = __expf(m_run[r] - mn);
            m_run[r] = mn;
        }
        float rs[4] = {0.f, 0.f, 0.f, 0.f};
#pragma unroll
        for (int nt = 0; nt < 4; ++nt)
#pragma unroll
            for (int r = 0; r < 4; ++r) {
                float p = __expf(sc_[nt][r] - m_run[r]);
                sc_[nt][r] = p;
                rs[r] += p;
            }
#pragma unroll
        for (int off = 1; off <= 8; off <<= 1)
#pragma unroll
            for (int r = 0; r < 4; ++r) rs[r] += __shfl_xor(rs[r], off, 64);
#pragma unroll
        for (int r = 0; r < 4; ++r) l_run[r] = l_run[r] * alpha[r] + rs[r];
#pragma unroll
        for (int t = 0; t < 8; ++t)
#pragma unroll
            for (int r = 0; r < 4; ++r) o[t][r] *= alpha[r];
        // P: C-layout -> LDS -> A-layout
#pragma unroll
        for (int nt = 0; nt < 4; ++nt)
#pragma unroll
            for (int r = 0; r < 4; ++r)
                Pb[wave][quad * 4 + r][nt * 16 + col] = (bf16)sc_[nt][r];
        __syncthreads();
        // O += P V
#pragma unroll
        for (int ks = 0; ks < 2; ++ks) {
            bf16x8 pa = *(const bf16x8*)(&Pb[wave][col][ks * 32 + quad * 8]);
#pragma unroll
            for (int nt = 0; nt < 8; ++nt) {
                bf16x8 bv = *(const bf16x8*)(&Vt[nt * 16 + col][ks * 32 + quad * 8]);
                o[nt] = MFMA16(pa, bv, o[nt]);
            }
        }
    }
    // epilogue: normalize and store fp32
#pragma unroll
    for (int r = 0; r < 4; ++r) {
        float inv = 1.0f / l_run[r];
        int row = qbase + wave * 16 + quad * 4 + r;
        float* orow = outg + ((size_t)bb * Sn + row) * Hn;
#pragma unroll
        for (int t = 0; t < 8; ++t)
            orow[t * 16 + col] = o[t][r] * inv;
    }
}

extern "C" void kernel_launch(void* const* d_in, const int* in_sizes, int n_in,
                              void* d_out, int out_size, void* d_ws, size_t ws_size,
                              hipStream_t stream) {
    const float* x     = (const float*)d_in[0];
    const float* w_dkv = (const float*)d_in[1];
    const float* w_k   = (const float*)d_in[2];
    const float* w_v   = (const float*)d_in[3];
    const float* w_q   = (const float*)d_in[4];

    float* out        = (float*)d_out;                   // [8,4096,128] fp32
    float* latent_out = out + (size_t)Mrows * Hn;        // [8,4096,64]  fp32

    char* ws = (char*)d_ws;
    bf16* q_ws   = (bf16*)(ws);                             // 8 MiB
    bf16* k_ws   = (bf16*)(ws + (size_t)8  * 1024 * 1024);  // 8 MiB
    bf16* v_ws   = (bf16*)(ws + (size_t)16 * 1024 * 1024);  // 8 MiB
    bf16* wT_dkv = (bf16*)(ws + (size_t)24 * 1024 * 1024);  // [64][2048]  256 KiB
    bf16* wT_q   = (bf16*)(ws + (size_t)24 * 1024 * 1024 + 512 * 1024); // [128][2048] 512 KiB

    transpose_cvt<<<(En * Ln + 255) / 256, 256, 0, stream>>>(w_dkv, wT_dkv, En, Ln);
    transpose_cvt<<<(En * Hn + 255) / 256, 256, 0, stream>>>(w_q, wT_q, En, Hn);
    gemm_xw<<<Mrows / 64, 256, 0, stream>>>(x, wT_dkv, wT_q, latent_out, q_ws);
    decompress_k<<<Mrows * Hn / 256, 256, 0, stream>>>(latent_out, w_k, k_ws);
    decompress_k<<<Mrows * Hn / 256, 256, 0, stream>>>(latent_out, w_v, v_ws);
    mla_attn<<<dim3(Sn / 64, Bn), 256, 0, stream>>>(q_ws, k_ws, v_ws, out);
}

// Round 3
// 673.868 us; speedup vs baseline: 1.2214x; 1.2214x over previous
//
#include <hip/hip_runtime.h>

typedef __bf16 bf16;
typedef __bf16 bf16x2 __attribute__((ext_vector_type(2)));
typedef __bf16 bf16x4 __attribute__((ext_vector_type(4)));
typedef __bf16 bf16x8 __attribute__((ext_vector_type(8)));
typedef float  f32x4  __attribute__((ext_vector_type(4)));

#define MFMA16(a,b,c) __builtin_amdgcn_mfma_f32_16x16x32_bf16((a),(b),(c),0,0,0)

constexpr int Bn = 8, Sn = 4096, En = 2048, Ln = 64, Hn = 128;
constexpr int Mrows = Bn * Sn; // 32768

__device__ __forceinline__ void load_lds_16(const bf16* g, bf16* l) {
    __builtin_amdgcn_global_load_lds(
        (const __attribute__((address_space(1))) uint32_t*)g,
        (__attribute__((address_space(3))) uint32_t*)l, 16, 0, 0);
}

// ---------------- transpose + fp32->bf16: in[K][N] -> out[N][K] ----------------
__global__ __launch_bounds__(256) void transpose_cvt(const float* __restrict__ in,
                                                     bf16* __restrict__ out,
                                                     int K, int N) {
    int tid = blockIdx.x * 256 + threadIdx.x;
    if (tid >= K * N) return;
    int k = tid / N, n = tid - k * N;
    out[n * K + k] = (bf16)in[tid];
}

// ---------------- fused latent+q GEMM: C = x @ [w_dkv | w_q] ----------------
// BM=64 (4 waves x 16 rows), BN=192 (12 n-tiles), BK=64, K=2048 (32 steps)
// A: fp32 x staged via VGPR cvt -> LDS (padded). B: bf16 wT staged via
// global_load_lds w/ XOR-swizzled layout (swizzle applied on global gather addr).
__global__ __launch_bounds__(256) void gemm_xw(const float* __restrict__ x,
                                               const bf16* __restrict__ wT,    // [192][2048]
                                               float* __restrict__ latent_out, // [32768][64] fp32
                                               bf16* __restrict__ q_out) {     // [32768][128] bf16
    __shared__ __align__(16) bf16 As[64 * 72];   // [row][k], +8 pad
    __shared__ __align__(16) bf16 Bs[192 * 64];  // [n][k] XOR-swizzled, unpadded
    const int lane = threadIdx.x & 63;
    const int wave = threadIdx.x >> 6;
    const int col  = lane & 15, quad = lane >> 4;
    const int mblock = blockIdx.x * 64;

    f32x4 acc[12];
#pragma unroll
    for (int t = 0; t < 12; ++t) acc[t] = (f32x4){0.f, 0.f, 0.f, 0.f};

    const int arow = (threadIdx.x >> 4);      // 0..15
    const int akc  = (threadIdx.x & 15);      // 0..15 (x4 floats)
    const int bsub = lane >> 3;               // 0..7 sub-row
    const int bkg0 = lane & 7;                // group id pre-swizzle

    for (int step = 0; step < 32; ++step) {
        __syncthreads();
        // --- B staging: 6 x global_load_lds per wave (8 rows x 128B each) ---
#pragma unroll
        for (int j = 0; j < 6; ++j) {
            int nr0 = wave * 48 + j * 8;
            int n = nr0 + bsub;
            int kgrp = bkg0 ^ bsub;            // XOR swizzle via global addr perm
            const bf16* g = wT + (size_t)n * En + step * 64 + kgrp * 8;
            load_lds_16(g, &Bs[nr0 * 64]);     // wave-uniform LDS base
        }
        // --- A staging: fp32 -> bf16 -> LDS, coalesced 256B rows ---
#pragma unroll
        for (int p = 0; p < 4; ++p) {
            int row = p * 16 + arow;
            f32x4 v = *(const f32x4*)(x + (size_t)(mblock + row) * En + step * 64 + akc * 4);
            bf16x4 c;
#pragma unroll
            for (int j = 0; j < 4; ++j) c[j] = (bf16)v[j];
            *(bf16x4*)(&As[row * 72 + akc * 4]) = c;
        }
        __syncthreads();
        // --- compute: 2 k-substeps x 12 n-tiles ---
#pragma unroll
        for (int ks2 = 0; ks2 < 2; ++ks2) {
            bf16x8 a = *(const bf16x8*)(&As[(wave * 16 + col) * 72 + ks2 * 32 + quad * 8]);
#pragma unroll
            for (int nt = 0; nt < 12; ++nt) {
                int n = nt * 16 + col;
                int sg = (ks2 * 4 + quad) ^ (col & 7);
                bf16x8 b = *(const bf16x8*)(&Bs[n * 64 + sg * 8]);
                acc[nt] = MFMA16(a, b, acc[nt]);
            }
        }
    }
#pragma unroll
    for (int t = 0; t < 12; ++t)
#pragma unroll
        for (int r = 0; r < 4; ++r) {
            int row = mblock + wave * 16 + quad * 4 + r;
            if (t < 4) latent_out[(size_t)row * Ln + t * 16 + col] = acc[t][r];
            else       q_out[(size_t)row * Hn + (t - 4) * 16 + col] = (bf16)acc[t][r];
        }
}

// ---------------- fused k+v decompression ----------------
__global__ __launch_bounds__(256) void decompress_kv(const float* __restrict__ latent, // [32768][64] fp32
                                                     const float* __restrict__ wk,     // [64][128] fp32
                                                     const float* __restrict__ wv,     // [64][128] fp32
                                                     bf16* __restrict__ k_out,         // [32768][128]
                                                     bf16* __restrict__ v_out) {       // [32768][128]
    int tid = blockIdx.x * 256 + threadIdx.x;
    int m = tid >> 7, h = tid & 127;
    const float* lrow = latent + (size_t)m * Ln;
    float a = 0.f, b = 0.f;
#pragma unroll
    for (int l = 0; l < Ln; ++l) {
        float lv = lrow[l];
        a += lv * wk[l * Hn + h];
        b += lv * wv[l * Hn + h];
    }
    k_out[tid] = (bf16)a;
    v_out[tid] = (bf16)b;
}

// ---------------- flash attention, causal, BQ=64 BK=64 D=128 ----------------
__global__ __launch_bounds__(256) void mla_attn(const bf16* __restrict__ qg,
                                                const bf16* __restrict__ kg,
                                                const bf16* __restrict__ vg,
                                                float* __restrict__ outg) {
    __shared__ __align__(16) bf16 Kt[64][136];    // [key][d], +8 pad
    __shared__ __align__(16) bf16 Vt[128][72];    // [d][key], +8 pad
    __shared__ __align__(16) bf16 Pb[4][16][72];  // per-wave P, [row][key], +8 pad
    const int lane = threadIdx.x & 63;
    const int wave = threadIdx.x >> 6;
    const int col  = lane & 15, quad = lane >> 4;
    const int bb    = blockIdx.y;
    const int qtile = (int)gridDim.x - 1 - (int)blockIdx.x; // big blocks first
    const int qbase = qtile * 64;
    const bf16* kb = kg + (size_t)bb * Sn * Hn;
    const bf16* vb = vg + (size_t)bb * Sn * Hn;

    bf16x8 qf[4];
    {
        const bf16* qrow = qg + ((size_t)bb * Sn + qbase + wave * 16 + col) * Hn;
#pragma unroll
        for (int ks = 0; ks < 4; ++ks)
            qf[ks] = *(const bf16x8*)(qrow + ks * 32 + quad * 8);
    }
    f32x4 o[8];
#pragma unroll
    for (int t = 0; t < 8; ++t) o[t] = (f32x4){0.f, 0.f, 0.f, 0.f};
    float m_run[4] = {-3.0e38f, -3.0e38f, -3.0e38f, -3.0e38f};
    float l_run[4] = {0.f, 0.f, 0.f, 0.f};
    const float scale = 0.08838834764831845f; // 1/sqrt(128)

    for (int kt = 0; kt <= qtile; ++kt) {
        __syncthreads();
        // stage K tile [64][128]
#pragma unroll
        for (int i = 0; i < 4; ++i) {
            int c = threadIdx.x + i * 256;
            int key = c >> 4, dc = c & 15;
            *(bf16x8*)(&Kt[key][dc * 8]) =
                *(const bf16x8*)(kb + (size_t)(kt * 64 + key) * Hn + dc * 8);
        }
        // stage V transposed -> Vt[d][key], 2 keys/thread, b32 writes
#pragma unroll
        for (int i = 0; i < 2; ++i) {
            int c = threadIdx.x + i * 256;          // 0..511
            int key0 = (c & 31) * 2, dc = c >> 5;   // dc 0..15
            const bf16* vp = vb + (size_t)(kt * 64 + key0) * Hn + dc * 8;
            bf16x8 v0 = *(const bf16x8*)(vp);
            bf16x8 v1 = *(const bf16x8*)(vp + Hn);
#pragma unroll
            for (int j = 0; j < 8; ++j) {
                bf16x2 pr; pr[0] = v0[j]; pr[1] = v1[j];
                *(bf16x2*)(&Vt[dc * 8 + j][key0]) = pr;
            }
        }
        __syncthreads();

        // S = Q K^T
        f32x4 sa[4];
#pragma unroll
        for (int nt = 0; nt < 4; ++nt) {
            sa[nt] = (f32x4){0.f, 0.f, 0.f, 0.f};
#pragma unroll
            for (int ks = 0; ks < 4; ++ks) {
                bf16x8 bfr = *(const bf16x8*)(&Kt[nt * 16 + col][ks * 32 + quad * 8]);
                sa[nt] = MFMA16(qf[ks], bfr, sa[nt]);
            }
        }
        float sc_[4][4];
        if (kt == qtile) {
#pragma unroll
            for (int nt = 0; nt < 4; ++nt)
#pragma unroll
                for (int r = 0; r < 4; ++r) {
                    float s = sa[nt][r] * scale;
                    if (nt * 16 + col > wave * 16 + quad * 4 + r) s = -1.0e30f;
                    sc_[nt][r] = s;
                }
        } else {
#pragma unroll
            for (int nt = 0; nt < 4; ++nt)
#pragma unroll
                for (int r = 0; r < 4; ++r) sc_[nt][r] = sa[nt][r] * scale;
        }
        // online softmax across quad's 16 lanes
        float mt[4];
#pragma unroll
        for (int r = 0; r < 4; ++r)
            mt[r] = fmaxf(fmaxf(sc_[0][r], sc_[1][r]), fmaxf(sc_[2][r], sc_[3][r]));
#pragma unroll
        for (int off = 1; off <= 8; off <<= 1)
#pragma unroll
            for (int r = 0; r < 4; ++r)
                mt[r] = fmaxf(mt[r], __shfl_xor(mt[r], off, 64));
        float alpha[4];
#pragma unroll
        for (int r = 0; r < 4; ++r) {
            float mn = fmaxf(m_run[r], mt[r]);
            alpha[r] = __expf(m_run[r] - mn);
            m_run[r] = mn;
        }
        float rs[4] = {0.f, 0.f, 0.f, 0.f};
#pragma unroll
        for (int nt = 0; nt < 4; ++nt)
#pragma unroll
            for (int r = 0; r < 4; ++r) {
                float p = __expf(sc_[nt][r] - m_run[r]);
                sc_[nt][r] = p;
                rs[r] += p;
            }
#pragma unroll
        for (int off = 1; off <= 8; off <<= 1)
#pragma unroll
            for (int r = 0; r < 4; ++r) rs[r] += __shfl_xor(rs[r], off, 64);
#pragma unroll
        for (int r = 0; r < 4; ++r) l_run[r] = l_run[r] * alpha[r] + rs[r];
#pragma unroll
        for (int t = 0; t < 8; ++t)
#pragma unroll
            for (int r = 0; r < 4; ++r) o[t][r] *= alpha[r];
        // P: C-layout -> LDS -> A-layout
#pragma unroll
        for (int nt = 0; nt < 4; ++nt)
#pragma unroll
            for (int r = 0; r < 4; ++r)
                Pb[wave][quad * 4 + r][nt * 16 + col] = (bf16)sc_[nt][r];
        __syncthreads();
        // O += P V
#pragma unroll
        for (int ks = 0; ks < 2; ++ks) {
            bf16x8 pa = *(const bf16x8*)(&Pb[wave][col][ks * 32 + quad * 8]);
#pragma unroll
            for (int nt = 0; nt < 8; ++nt) {
                bf16x8 bv = *(const bf16x8*)(&Vt[nt * 16 + col][ks * 32 + quad * 8]);
                o[nt] = MFMA16(pa, bv, o[nt]);
            }
        }
    }
#pragma unroll
    for (int r = 0; r < 4; ++r) {
        float inv = 1.0f / l_run[r];
        int row = qbase + wave * 16 + quad * 4 + r;
        float* orow = outg + ((size_t)bb * Sn + row) * Hn;
#pragma unroll
        for (int t = 0; t < 8; ++t)
            orow[t * 16 + col] = o[t][r] * inv;
    }
}

extern "C" void kernel_launch(void* const* d_in, const int* in_sizes, int n_in,
                              void* d_out, int out_size, void* d_ws, size_t ws_size,
                              hipStream_t stream) {
    const float* x     = (const float*)d_in[0];
    const float* w_dkv = (const float*)d_in[1];
    const float* w_k   = (const float*)d_in[2];
    const float* w_v   = (const float*)d_in[3];
    const float* w_q   = (const float*)d_in[4];

    float* out        = (float*)d_out;                   // [8,4096,128] fp32
    float* latent_out = out + (size_t)Mrows * Hn;        // [8,4096,64]  fp32

    char* ws = (char*)d_ws;
    bf16* q_ws = (bf16*)(ws);                             // 8 MiB
    bf16* k_ws = (bf16*)(ws + (size_t)8  * 1024 * 1024);  // 8 MiB
    bf16* v_ws = (bf16*)(ws + (size_t)16 * 1024 * 1024);  // 8 MiB
    bf16* wT   = (bf16*)(ws + (size_t)24 * 1024 * 1024);  // [192][2048] bf16, 768 KiB

    // combined wT: rows 0..63 = w_dkv^T, rows 64..191 = w_q^T
    transpose_cvt<<<(En * Ln + 255) / 256, 256, 0, stream>>>(w_dkv, wT, En, Ln);
    transpose_cvt<<<(En * Hn + 255) / 256, 256, 0, stream>>>(w_q, wT + (size_t)64 * En, En, Hn);
    gemm_xw<<<Mrows / 64, 256, 0, stream>>>(x, wT, latent_out, q_ws);
    decompress_kv<<<Mrows * Hn / 256, 256, 0, stream>>>(latent_out, w_k, w_v, k_ws, v_ws);
    mla_attn<<<dim3(Sn / 64, Bn), 256, 0, stream>>>(q_ws, k_ws, v_ws, out);
}

// Round 4
// 670.023 us; speedup vs baseline: 1.2284x; 1.0057x over previous
//
#include <hip/hip_runtime.h>

typedef __bf16 bf16;
typedef __bf16 bf16x2 __attribute__((ext_vector_type(2)));
typedef __bf16 bf16x4 __attribute__((ext_vector_type(4)));
typedef __bf16 bf16x8 __attribute__((ext_vector_type(8)));
typedef float  f32x4  __attribute__((ext_vector_type(4)));

#define MFMA16(a,b,c) __builtin_amdgcn_mfma_f32_16x16x32_bf16((a),(b),(c),0,0,0)

constexpr int Bn = 8, Sn = 4096, En = 2048, Ln = 64, Hn = 128;
constexpr int Mrows = Bn * Sn; // 32768

__device__ __forceinline__ void load_lds_16(const bf16* g, bf16* l) {
    __builtin_amdgcn_global_load_lds(
        (const __attribute__((address_space(1))) uint32_t*)g,
        (__attribute__((address_space(3))) uint32_t*)l, 16, 0, 0);
}

// ---------------- transpose + fp32->bf16: in[K][N] -> out[N][K] ----------------
__global__ __launch_bounds__(256) void transpose_cvt(const float* __restrict__ in,
                                                     bf16* __restrict__ out,
                                                     int K, int N) {
    int tid = blockIdx.x * 256 + threadIdx.x;
    if (tid >= K * N) return;
    int k = tid / N, n = tid - k * N;
    out[n * K + k] = (bf16)in[tid];
}

// ---------------- fused latent+q GEMM: C = x @ [w_dkv | w_q] ----------------
// 512 threads = 8 waves: wave = (mgrp 0..3) x (nhalf 0..1). BM=64, BN=192, BK=64.
__global__ __launch_bounds__(512) void gemm_xw(const float* __restrict__ x,
                                               const bf16* __restrict__ wT,    // [192][2048]
                                               float* __restrict__ latent_out, // [32768][64] fp32
                                               bf16* __restrict__ q_out) {     // [32768][128] bf16
    __shared__ __align__(16) bf16 As[64 * 72];   // [row][k], +8 pad
    __shared__ __align__(16) bf16 Bs[192 * 64];  // [n][k] XOR-swizzled, unpadded
    const int lane = threadIdx.x & 63;
    const int wave = threadIdx.x >> 6;           // 0..7
    const int col  = lane & 15, quad = lane >> 4;
    const int mgrp  = wave >> 1;                 // 0..3 : rows mgrp*16..+16
    const int nhalf = wave & 1;                  // 0..1 : nt 0..5 / 6..11
    const int mblock = blockIdx.x * 64;

    f32x4 acc[6];
#pragma unroll
    for (int t = 0; t < 6; ++t) acc[t] = (f32x4){0.f, 0.f, 0.f, 0.f};

    const int bsub = lane >> 3;             // 0..7 sub-row for B staging
    const int bkg0 = lane & 7;
    const int akc  = threadIdx.x & 15;      // 0..15 f32x4 column
    const int arow0 = threadIdx.x >> 4;     // 0..31

    for (int step = 0; step < 32; ++step) {
        __syncthreads();
        // --- B staging: 3 x global_load_lds per wave (8 rows x 128B each) ---
#pragma unroll
        for (int j = 0; j < 3; ++j) {
            int nr0 = wave * 24 + j * 8;
            int n = nr0 + bsub;
            int kgrp = bkg0 ^ bsub;            // XOR swizzle via global addr perm
            const bf16* g = wT + (size_t)n * En + step * 64 + kgrp * 8;
            load_lds_16(g, &Bs[nr0 * 64]);
        }
        // --- A staging: fp32 -> bf16 -> LDS, fully coalesced 16B/lane ---
#pragma unroll
        for (int p = 0; p < 2; ++p) {
            int row = p * 32 + arow0;
            f32x4 v = *(const f32x4*)(x + (size_t)(mblock + row) * En + step * 64 + akc * 4);
            bf16x4 c;
#pragma unroll
            for (int j = 0; j < 4; ++j) c[j] = (bf16)v[j];
            *(bf16x4*)(&As[row * 72 + akc * 4]) = c;
        }
        __syncthreads();
        // --- compute: 2 k-substeps x 6 n-tiles per wave ---
#pragma unroll
        for (int ks2 = 0; ks2 < 2; ++ks2) {
            bf16x8 a = *(const bf16x8*)(&As[(mgrp * 16 + col) * 72 + ks2 * 32 + quad * 8]);
#pragma unroll
            for (int t = 0; t < 6; ++t) {
                int n = nhalf * 96 + t * 16 + col;
                int sg = (ks2 * 4 + quad) ^ (col & 7);
                bf16x8 b = *(const bf16x8*)(&Bs[n * 64 + sg * 8]);
                acc[t] = MFMA16(a, b, acc[t]);
            }
        }
    }
#pragma unroll
    for (int t = 0; t < 6; ++t) {
        int gnt = nhalf * 6 + t;
#pragma unroll
        for (int r = 0; r < 4; ++r) {
            int row = mblock + mgrp * 16 + quad * 4 + r;
            if (gnt < 4) latent_out[(size_t)row * Ln + gnt * 16 + col] = acc[t][r];
            else         q_out[(size_t)row * Hn + (gnt - 4) * 16 + col] = (bf16)acc[t][r];
        }
    }
}

// ---------------- fused k+v decompression ----------------
__global__ __launch_bounds__(256) void decompress_kv(const float* __restrict__ latent, // [32768][64]
                                                     const float* __restrict__ wk,     // [64][128]
                                                     const float* __restrict__ wv,     // [64][128]
                                                     bf16* __restrict__ k_out,
                                                     bf16* __restrict__ v_out) {
    int tid = blockIdx.x * 256 + threadIdx.x;
    int m = tid >> 7, h = tid & 127;
    const float* lrow = latent + (size_t)m * Ln;
    float a = 0.f, b = 0.f;
#pragma unroll
    for (int l = 0; l < Ln; ++l) {
        float lv = lrow[l];
        a += lv * wk[l * Hn + h];
        b += lv * wv[l * Hn + h];
    }
    k_out[tid] = (bf16)a;
    v_out[tid] = (bf16)b;
}

// ---------------- flash attention, causal, BQ=64 BK=64 D=128 ----------------
// 1D grid, globally work-descending: rank -> qtile = 63 - rank/8, bb = rank%8
__global__ __launch_bounds__(256, 3) void mla_attn(const bf16* __restrict__ qg,
                                                   const bf16* __restrict__ kg,
                                                   const bf16* __restrict__ vg,
                                                   float* __restrict__ outg) {
    __shared__ __align__(16) bf16 Ks[64 * 128];   // [key][d] XOR-swizzled, unpadded (DMA)
    __shared__ __align__(16) bf16 Vt[128][72];    // [d][key], +8 pad
    __shared__ __align__(16) bf16 Pb[4][16][72];  // per-wave P, XOR-swizzled cols
    const int lane = threadIdx.x & 63;
    const int wave = threadIdx.x >> 6;
    const int col  = lane & 15, quad = lane >> 4;
    const int rank  = blockIdx.x;
    const int qtile = 63 - (rank >> 3);
    const int bb    = rank & 7;
    const int qbase = qtile * 64;
    const bf16* kb = kg + (size_t)bb * Sn * Hn;
    const bf16* vb = vg + (size_t)bb * Sn * Hn;

    bf16x8 qf[4];
    {
        const bf16* qrow = qg + ((size_t)bb * Sn + qbase + wave * 16 + col) * Hn;
#pragma unroll
        for (int ks = 0; ks < 4; ++ks)
            qf[ks] = *(const bf16x8*)(qrow + ks * 32 + quad * 8);
    }
    f32x4 o[8];
#pragma unroll
    for (int t = 0; t < 8; ++t) o[t] = (f32x4){0.f, 0.f, 0.f, 0.f};
    float m_run[4] = {-3.0e38f, -3.0e38f, -3.0e38f, -3.0e38f};
    float l_run[4] = {0.f, 0.f, 0.f, 0.f};
    const float scale = 0.08838834764831845f; // 1/sqrt(128)

    for (int kt = 0; kt <= qtile; ++kt) {
        __syncthreads();
        // --- K staging: global_load_lds, 4 instrs/wave, 4 keys each ---
#pragma unroll
        for (int ii = 0; ii < 4; ++ii) {
            int i = wave * 4 + ii;               // 0..15
            int key = 4 * i + (lane >> 4);
            int p = lane & 15;
            int g = (p & 8) | ((p & 7) ^ (key & 7));  // swizzle on global side
            const bf16* src = kb + (size_t)(kt * 64 + key) * Hn + g * 8;
            load_lds_16(src, Ks + i * 512);
        }
        // --- V staging transposed -> Vt[d][key], b32 pair writes ---
#pragma unroll
        for (int i = 0; i < 2; ++i) {
            int c = threadIdx.x + i * 256;          // 0..511
            int key0 = (c & 31) * 2, dc = c >> 5;   // dc 0..15
            const bf16* vp = vb + (size_t)(kt * 64 + key0) * Hn + dc * 8;
            bf16x8 v0 = *(const bf16x8*)(vp);
            bf16x8 v1 = *(const bf16x8*)(vp + Hn);
#pragma unroll
            for (int j = 0; j < 8; ++j) {
                bf16x2 pr; pr[0] = v0[j]; pr[1] = v1[j];
                *(bf16x2*)(&Vt[dc * 8 + j][key0]) = pr;
            }
        }
        __syncthreads();   // also drains the K DMA (vmcnt) per-wave

        // --- S = Q K^T (reads swizzled Ks) ---
        f32x4 sa[4];
#pragma unroll
        for (int nt = 0; nt < 4; ++nt) {
            sa[nt] = (f32x4){0.f, 0.f, 0.f, 0.f};
#pragma unroll
            for (int ks = 0; ks < 4; ++ks) {
                int key = nt * 16 + col;
                int g = ks * 4 + quad;
                int pos = (g & 8) | ((g & 7) ^ (col & 7));
                bf16x8 bfr = *(const bf16x8*)(Ks + key * 128 + pos * 8);
                sa[nt] = MFMA16(qf[ks], bfr, sa[nt]);
            }
        }
        float sc_[4][4];
        if (kt == qtile) {
#pragma unroll
            for (int nt = 0; nt < 4; ++nt)
#pragma unroll
                for (int r = 0; r < 4; ++r) {
                    float s = sa[nt][r] * scale;
                    if (nt * 16 + col > wave * 16 + quad * 4 + r) s = -1.0e30f;
                    sc_[nt][r] = s;
                }
        } else {
#pragma unroll
            for (int nt = 0; nt < 4; ++nt)
#pragma unroll
                for (int r = 0; r < 4; ++r) sc_[nt][r] = sa[nt][r] * scale;
        }
        // --- online softmax across quad's 16 lanes ---
        float mt[4];
#pragma unroll
        for (int r = 0; r < 4; ++r)
            mt[r] = fmaxf(fmaxf(sc_[0][r], sc_[1][r]), fmaxf(sc_[2][r], sc_[3][r]));
#pragma unroll
        for (int off = 1; off <= 8; off <<= 1)
#pragma unroll
            for (int r = 0; r < 4; ++r)
                mt[r] = fmaxf(mt[r], __shfl_xor(mt[r], off, 64));
        float alpha[4];
#pragma unroll
        for (int r = 0; r < 4; ++r) {
            float mn = fmaxf(m_run[r], mt[r]);
            alpha[r] = __expf(m_run[r] - mn);
            m_run[r] = mn;
        }
        float rs[4] = {0.f, 0.f, 0.f, 0.f};
#pragma unroll
        for (int nt = 0; nt < 4; ++nt)
#pragma unroll
            for (int r = 0; r < 4; ++r) {
                float p = __expf(sc_[nt][r] - m_run[r]);
                sc_[nt][r] = p;
                rs[r] += p;
            }
#pragma unroll
        for (int off = 1; off <= 8; off <<= 1)
#pragma unroll
            for (int r = 0; r < 4; ++r) rs[r] += __shfl_xor(rs[r], off, 64);
#pragma unroll
        for (int r = 0; r < 4; ++r) l_run[r] = l_run[r] * alpha[r] + rs[r];
#pragma unroll
        for (int t = 0; t < 8; ++t)
#pragma unroll
            for (int r = 0; r < 4; ++r) o[t][r] *= alpha[r];
        // --- P: C-layout -> LDS (swizzled, wave-private: NO barrier needed) ---
#pragma unroll
        for (int nt = 0; nt < 4; ++nt)
#pragma unroll
            for (int r = 0; r < 4; ++r)
                Pb[wave][quad * 4 + r][((nt ^ quad) & 3) * 16 + col] = (bf16)sc_[nt][r];
        // --- O += P V ---
#pragma unroll
        for (int ks = 0; ks < 2; ++ks) {
            int pos = (ks * 32 + quad * 8) ^ ((col >> 2) * 16);
            bf16x8 pa = *(const bf16x8*)(&Pb[wave][col][pos]);
#pragma unroll
            for (int nt = 0; nt < 8; ++nt) {
                bf16x8 bv = *(const bf16x8*)(&Vt[nt * 16 + col][ks * 32 + quad * 8]);
                o[nt] = MFMA16(pa, bv, o[nt]);
            }
        }
    }
#pragma unroll
    for (int r = 0; r < 4; ++r) {
        float inv = 1.0f / l_run[r];
        int row = qbase + wave * 16 + quad * 4 + r;
        float* orow = outg + ((size_t)bb * Sn + row) * Hn;
#pragma unroll
        for (int t = 0; t < 8; ++t)
            orow[t * 16 + col] = o[t][r] * inv;
    }
}

extern "C" void kernel_launch(void* const* d_in, const int* in_sizes, int n_in,
                              void* d_out, int out_size, void* d_ws, size_t ws_size,
                              hipStream_t stream) {
    const float* x     = (const float*)d_in[0];
    const float* w_dkv = (const float*)d_in[1];
    const float* w_k   = (const float*)d_in[2];
    const float* w_v   = (const float*)d_in[3];
    const float* w_q   = (const float*)d_in[4];

    float* out        = (float*)d_out;                   // [8,4096,128] fp32
    float* latent_out = out + (size_t)Mrows * Hn;        // [8,4096,64]  fp32

    char* ws = (char*)d_ws;
    bf16* q_ws = (bf16*)(ws);                             // 8 MiB
    bf16* k_ws = (bf16*)(ws + (size_t)8  * 1024 * 1024);  // 8 MiB
    bf16* v_ws = (bf16*)(ws + (size_t)16 * 1024 * 1024);  // 8 MiB
    bf16* wT   = (bf16*)(ws + (size_t)24 * 1024 * 1024);  // [192][2048] bf16, 768 KiB

    transpose_cvt<<<(En * Ln + 255) / 256, 256, 0, stream>>>(w_dkv, wT, En, Ln);
    transpose_cvt<<<(En * Hn + 255) / 256, 256, 0, stream>>>(w_q, wT + (size_t)64 * En, En, Hn);
    gemm_xw<<<Mrows / 64, 512, 0, stream>>>(x, wT, latent_out, q_ws);
    decompress_kv<<<Mrows * Hn / 256, 256, 0, stream>>>(latent_out, w_k, w_v, k_ws, v_ws);
    mla_attn<<<Sn / 64 * Bn, 256, 0, stream>>>(q_ws, k_ws, v_ws, out);
}